// Round 1
// baseline (213.732 us; speedup 1.0000x reference)
//
#include <hip/hip_runtime.h>
#include <math.h>

// Problem constants (from setup_inputs)
#define BB   16
#define HH   112
#define WW   112
#define CC   64
#define KK   8
#define EPSF 1e-6f

#define WPT  7              // outputs in w per thread
#define NCOL (WPT + 8)      // 15 columns incl. +/-4 halo
// block: 256 threads = 64 channels x 4 w-groups -> covers 28 w positions
// grid:  B * H * (W/28) = 16*112*4 = 7168 blocks

__global__ __launch_bounds__(256)
void l2hist_singularity_kernel(const float* __restrict__ x,
                               const float* __restrict__ sw,
                               const float* __restrict__ centers,
                               const float* __restrict__ widths,
                               float* __restrict__ out)
{
    const int tid = threadIdx.x;
    const int c   = tid & 63;        // lanes contiguous in channel -> coalesced
    const int wq  = tid >> 6;        // 0..3 (one wave per w-group)

    const int blk = blockIdx.x;
    const int wt  = blk & 3;                 // w-tile (4 per row)
    const int h   = (blk >> 2) % HH;
    const int b   = (blk >> 2) / HH;
    const int w0  = wt * 28 + wq * WPT;      // first output w for this thread

    // scalar weights (wave-uniform)
    const float s1 = sw[0], s2 = sw[1], s3 = sw[2], s4 = sw[3];

    // per-channel histogram params, cached in registers
    float cen[KK], wid[KK];
#pragma unroll
    for (int k = 0; k < KK; ++k) {
        cen[k] = centers[c * KK + k];
        wid[k] = widths[c * KK + k];
    }

    const size_t base_b = (size_t)b * HH * WW * CC;

    // vertical (column) box sums for 4 radii, 15 columns, fully static arrays
    float v1[NCOL], v2[NCOL], v3[NCOL], v4[NCOL];

#pragma unroll
    for (int i = 0; i < NCOL; ++i) {
        const int wc = w0 - 4 + i;
        float a0, a1, a2, a3, a4, a5, a6, a7, a8;
        if (wc >= 0 && wc < WW) {
            const size_t colbase = base_b + (size_t)wc * CC + c;
            // row h+dh, dh = -4..4 ; zero for out-of-bounds rows (SAME pad)
            a0 = (h - 4 >= 0) ? fabsf(x[colbase + (size_t)(h - 4) * WW * CC]) + EPSF : 0.0f;
            a1 = (h - 3 >= 0) ? fabsf(x[colbase + (size_t)(h - 3) * WW * CC]) + EPSF : 0.0f;
            a2 = (h - 2 >= 0) ? fabsf(x[colbase + (size_t)(h - 2) * WW * CC]) + EPSF : 0.0f;
            a3 = (h - 1 >= 0) ? fabsf(x[colbase + (size_t)(h - 1) * WW * CC]) + EPSF : 0.0f;
            a4 =                fabsf(x[colbase + (size_t)h       * WW * CC]) + EPSF;
            a5 = (h + 1 < HH) ? fabsf(x[colbase + (size_t)(h + 1) * WW * CC]) + EPSF : 0.0f;
            a6 = (h + 2 < HH) ? fabsf(x[colbase + (size_t)(h + 2) * WW * CC]) + EPSF : 0.0f;
            a7 = (h + 3 < HH) ? fabsf(x[colbase + (size_t)(h + 3) * WW * CC]) + EPSF : 0.0f;
            a8 = (h + 4 < HH) ? fabsf(x[colbase + (size_t)(h + 4) * WW * CC]) + EPSF : 0.0f;
        } else {
            a0 = a1 = a2 = a3 = a4 = a5 = a6 = a7 = a8 = 0.0f;
        }
        const float t1 = a3 + a4 + a5;        // 3-window vertical
        const float t2 = t1 + a2 + a6;        // 5
        const float t3 = t2 + a1 + a7;        // 7
        const float t4 = t3 + a0 + a8;        // 9
        v1[i] = t1; v2[i] = t2; v3[i] = t3; v4[i] = t4;
    }

#pragma unroll
    for (int wi = 0; wi < WPT; ++wi) {
        const int ci = wi + 4;   // center column index in v arrays

        const float mu1 = v1[ci - 1] + v1[ci] + v1[ci + 1];
        const float mu2 = v2[ci - 2] + v2[ci - 1] + v2[ci] + v2[ci + 1] + v2[ci + 2];
        const float mu3 = v3[ci - 3] + v3[ci - 2] + v3[ci - 1] + v3[ci] +
                          v3[ci + 1] + v3[ci + 2] + v3[ci + 3];
        const float mu4 = v4[ci - 4] + v4[ci - 3] + v4[ci - 2] + v4[ci - 1] + v4[ci] +
                          v4[ci + 1] + v4[ci + 2] + v4[ci + 3] + v4[ci + 4];

        const float alpha = s1 * __logf(mu1) + s2 * __logf(mu2) +
                            s3 * __logf(mu3) + s4 * __logf(mu4);

        float sc = 0.0f;
#pragma unroll
        for (int k = 0; k < KK; ++k) {
            const float d  = alpha - cen[k];
            const float hv = 1.0f - wid[k] * d * d;
            sc += fmaxf(hv, 0.0f);
        }

        const float sig = 1.0f / (1.0f + __expf(-sc));

        const size_t idx = base_b + ((size_t)h * WW + (w0 + wi)) * CC + c;
        out[idx] = x[idx] + sig;
    }
}

extern "C" void kernel_launch(void* const* d_in, const int* in_sizes, int n_in,
                              void* d_out, int out_size, void* d_ws, size_t ws_size,
                              hipStream_t stream) {
    const float* x       = (const float*)d_in[0];
    const float* sw      = (const float*)d_in[1];
    const float* centers = (const float*)d_in[2];
    const float* widths  = (const float*)d_in[3];
    float* out           = (float*)d_out;

    const int blocks = BB * HH * (WW / 28);   // 7168
    l2hist_singularity_kernel<<<blocks, 256, 0, stream>>>(x, sw, centers, widths, out);
}

// Round 2
// 58.480 us; speedup vs baseline: 3.6548x; 3.6548x over previous
//
#include <hip/hip_runtime.h>
#include <math.h>

// Problem constants (from setup_inputs)
#define BB   16
#define HH   112
#define WW   112
#define CC   64
#define KK   8
#define EPSF 1e-6f

#define WPT  7              // outputs in w per thread
#define NCOL 15             // WPT + 8 halo columns
#define LN2F 0.69314718055994530942f

// Load a chunk of NC columns x 9 rows unconditionally into registers, then
// reduce into the mu window accumulators. All indices compile-time static.
template<bool HE, bool WE, int I0, int NC>
__device__ __forceinline__ void process_chunk(const float* __restrict__ x,
                                              const int* rowbase,
                                              const float* rvalid,
                                              int w0, int c,
                                              float* mu1, float* mu2,
                                              float* mu3, float* mu4)
{
    float a[NC][9];
    int coloff[NC];
#pragma unroll
    for (int j = 0; j < NC; ++j) {
        int wc = w0 - 4 + I0 + j;
        int wcc = WE ? min(max(wc, 0), WW - 1) : wc;   // clamp -> always-valid addr
        coloff[j] = wcc * CC + c;
    }
    // ---- load phase: NC*9 unconditional loads, no value deps -> deep clause
#pragma unroll
    for (int j = 0; j < NC; ++j) {
#pragma unroll
        for (int dh = 0; dh < 9; ++dh) {
            a[j][dh] = x[rowbase[dh] + coloff[j]];
        }
    }
    // ---- consume phase
#pragma unroll
    for (int j = 0; j < NC; ++j) {
        const int i = I0 + j;
        float v0 = fabsf(a[j][0]);
        float v1 = fabsf(a[j][1]);
        float v2 = fabsf(a[j][2]);
        float v3 = fabsf(a[j][3]);
        float v4 = fabsf(a[j][4]);
        float v5 = fabsf(a[j][5]);
        float v6 = fabsf(a[j][6]);
        float v7 = fabsf(a[j][7]);
        float v8 = fabsf(a[j][8]);
        if (HE) {   // zero out-of-bounds rows (SAME zero padding)
            v0 *= rvalid[0]; v1 *= rvalid[1]; v2 *= rvalid[2]; v3 *= rvalid[3];
            v4 *= rvalid[4]; v5 *= rvalid[5]; v6 *= rvalid[6]; v7 *= rvalid[7];
            v8 *= rvalid[8];
        }
        float t1 = v3 + v4 + v5;      // vertical 3-window
        float t2 = t1 + v2 + v6;      // 5
        float t3 = t2 + v1 + v7;      // 7
        float t4 = t3 + v0 + v8;      // 9
        if (WE) {   // zero out-of-bounds columns
            const bool ok = (unsigned)(w0 - 4 + i) < (unsigned)WW;
            t1 = ok ? t1 : 0.0f;
            t2 = ok ? t2 : 0.0f;
            t3 = ok ? t3 : 0.0f;
            t4 = ok ? t4 : 0.0f;
        }
        // accumulate into every horizontal window containing column i
#pragma unroll
        for (int wi = 0; wi < WPT; ++wi) {
            const int ci = wi + 4;
            if (i >= ci - 1 && i <= ci + 1) mu1[wi] += t1;
            if (i >= ci - 2 && i <= ci + 2) mu2[wi] += t2;
            if (i >= ci - 3 && i <= ci + 3) mu3[wi] += t3;
            if (i >= ci - 4 && i <= ci + 4) mu4[wi] += t4;
        }
    }
}

template<bool HE, bool WE>
__device__ __forceinline__ void do_tile(const float* __restrict__ x,
                                        float* __restrict__ out,
                                        int b, int h, int w0, int c,
                                        float s1, float s2, float s3, float s4,
                                        const float* cen, const float* wid)
{
    int rowbase[9];        // block-uniform element offsets of the 9 rows
    float rvalid[9];
#pragma unroll
    for (int dh = 0; dh < 9; ++dh) {
        const int hr = h + dh - 4;
        const int hc = HE ? min(max(hr, 0), HH - 1) : hr;
        rowbase[dh] = ((b * HH + hc) * WW) * CC;
        rvalid[dh] = HE ? (((unsigned)hr < (unsigned)HH) ? 1.0f : 0.0f) : 1.0f;
    }

    float mu1[WPT], mu2[WPT], mu3[WPT], mu4[WPT];
#pragma unroll
    for (int i = 0; i < WPT; ++i) { mu1[i] = 0.f; mu2[i] = 0.f; mu3[i] = 0.f; mu4[i] = 0.f; }

    process_chunk<HE, WE, 0, 8>(x, rowbase, rvalid, w0, c, mu1, mu2, mu3, mu4);
    process_chunk<HE, WE, 8, 7>(x, rowbase, rvalid, w0, c, mu1, mu2, mu3, mu4);

    // eps correction: sum(|x|+eps) over window == sum(|x|) + n_valid*eps
    int rows1 = 3, rows2 = 5, rows3 = 7, rows4 = 9;
    if (HE) {
        rows1 = min(h + 1, HH - 1) - max(h - 1, 0) + 1;
        rows2 = min(h + 2, HH - 1) - max(h - 2, 0) + 1;
        rows3 = min(h + 3, HH - 1) - max(h - 3, 0) + 1;
        rows4 = min(h + 4, HH - 1) - max(h - 4, 0) + 1;
    }

#pragma unroll
    for (int wi = 0; wi < WPT; ++wi) {
        float e1, e2, e3, e4;
        if (WE) {
            const int w = w0 + wi;
            const int cols1 = min(w + 1, WW - 1) - max(w - 1, 0) + 1;
            const int cols2 = min(w + 2, WW - 1) - max(w - 2, 0) + 1;
            const int cols3 = min(w + 3, WW - 1) - max(w - 3, 0) + 1;
            const int cols4 = min(w + 4, WW - 1) - max(w - 4, 0) + 1;
            e1 = (float)(rows1 * cols1) * EPSF;
            e2 = (float)(rows2 * cols2) * EPSF;
            e3 = (float)(rows3 * cols3) * EPSF;
            e4 = (float)(rows4 * cols4) * EPSF;
        } else {
            e1 = (float)(rows1 * 3) * EPSF;   // interior: compile-time 9/25/49/81 * eps
            e2 = (float)(rows2 * 5) * EPSF;
            e3 = (float)(rows3 * 7) * EPSF;
            e4 = (float)(rows4 * 9) * EPSF;
        }

        // alpha = sum_r s_r * ln(mu_r); s_r pre-multiplied by ln2, use log2
        const float alpha = s1 * __log2f(mu1[wi] + e1) + s2 * __log2f(mu2[wi] + e2) +
                            s3 * __log2f(mu3[wi] + e3) + s4 * __log2f(mu4[wi] + e4);

        float sc = 0.0f;
#pragma unroll
        for (int k = 0; k < KK; ++k) {
            const float d  = alpha - cen[k];
            const float hv = 1.0f - wid[k] * (d * d);
            sc += fmaxf(hv, 0.0f);
        }

        const float sig = 1.0f / (1.0f + __expf(-sc));

        const int idx = rowbase[4] + (w0 + wi) * CC + c;
        out[idx] = x[idx] + sig;
    }
}

__global__ __launch_bounds__(256, 3)
void l2hist_singularity_kernel(const float* __restrict__ x,
                               const float* __restrict__ sw,
                               const float* __restrict__ centers,
                               const float* __restrict__ widths,
                               float* __restrict__ out)
{
    const int tid = threadIdx.x;
    const int c   = tid & 63;        // lanes contiguous in channel -> coalesced
    const int wq  = tid >> 6;        // 0..3 (wave index; w0 is wave-uniform)

    const int blk = blockIdx.x;
    const int wt  = blk & 3;
    const int h   = (blk >> 2) % HH;
    const int b   = (blk >> 2) / HH;
    const int w0  = wt * 28 + wq * WPT;

    // fold ln2 into the slope weights (we use hardware log2)
    const float s1 = sw[0] * LN2F, s2 = sw[1] * LN2F;
    const float s3 = sw[2] * LN2F, s4 = sw[3] * LN2F;

    float cen[KK], wid[KK];
#pragma unroll
    for (int k = 0; k < KK; ++k) {
        cen[k] = centers[c * KK + k];
        wid[k] = widths[c * KK + k];
    }

    const bool he = (h < 4) | (h >= HH - 4);                 // block-uniform
    const bool we = (w0 < 4) | (w0 + WPT - 1 + 4 >= WW);     // wave-uniform

    if (!he) {
        if (!we) do_tile<false, false>(x, out, b, h, w0, c, s1, s2, s3, s4, cen, wid);
        else     do_tile<false, true >(x, out, b, h, w0, c, s1, s2, s3, s4, cen, wid);
    } else {
        if (!we) do_tile<true,  false>(x, out, b, h, w0, c, s1, s2, s3, s4, cen, wid);
        else     do_tile<true,  true >(x, out, b, h, w0, c, s1, s2, s3, s4, cen, wid);
    }
}

extern "C" void kernel_launch(void* const* d_in, const int* in_sizes, int n_in,
                              void* d_out, int out_size, void* d_ws, size_t ws_size,
                              hipStream_t stream) {
    const float* x       = (const float*)d_in[0];
    const float* sw      = (const float*)d_in[1];
    const float* centers = (const float*)d_in[2];
    const float* widths  = (const float*)d_in[3];
    float* out           = (float*)d_out;

    const int blocks = BB * HH * (WW / 28);   // 7168
    l2hist_singularity_kernel<<<blocks, 256, 0, stream>>>(x, sw, centers, widths, out);
}